// Round 13
// baseline (398.392 us; speedup 1.0000x reference)
//
#include <hip/hip_runtime.h>

#define DEVI __device__ __forceinline__

DEVI float b2f(unsigned short u){
  union { unsigned u; float f; } v; v.u = ((unsigned)u) << 16; return v.f;
}
DEVI unsigned short f2b(float f){
  union { float f; unsigned u; } v; v.f = f;
  unsigned r = (v.u + 0x7fffu + ((v.u >> 16) & 1u)) >> 16;
  return (unsigned short)r;
}
// jax.nn.softplus(x) = max(x,0) + log1p(exp(-|x|))
DEVI float splus(float x){ return fmaxf(x, 0.f) + log1pf(expf(-fabsf(x))); }
DEVI float mila(float x){ return x * tanhf(splus(x - 1.f)); }
DEVI float ssp_(float x){ return splus(x) + 0.001f; }
// dist accessor: raw input, bf16 or f32 per flag
DEVI float rdist(const void* p, long idx, bool isbf){
  return isbf ? b2f(((const unsigned short*)p)[idx]) : ((const float*)p)[idx];
}

// ---------------- workspace layout (float elements) ----------------
constexpr int OFF_N   = 0;        // feats/nodes [2][128][64]
constexpr int OFF_E   = 16384;    // edges [2][512][64]
constexpr int OFF_A1  = 81920;    // [128][64]  f1 @ W0[0:64]
constexpr int OFF_A2  = 90112;    // [64][128]T f2 @ W0[64:128] + b0
constexpr int OFF_B1  = 98304;    // [128][64]  f1 @ W0[64:128] + b0
constexpr int OFF_B2  = 106496;   // [64][128]T f2 @ W0[0:64]
constexpr int OFF_APT = 114688;   // [2][5][128] ap outputs, transposed
constexpr int OFF_HM  = 115968;   // [2][128] argmax==0 mask
constexpr int OFF_PAR = 116224;   // [16384][5] pair params (atomically summed)
constexpr int OFF_MU1 = 198144;   // [64][128][4]
constexpr int OFF_MU2 = 230912;   // [64][128][4]
constexpr int OFF_ACC = 263680;   // [4][64]: es, in, ex, disp
constexpr int OFF_FLAG= 263936;   // 1.0 if inputs bf16, 0.0 if f32
constexpr int OFF_MIR = 264192;   // f32 mirror of all float inputs EXCEPT dist
constexpr int MTOT    = 162698;   // mirror size (dist excluded)
constexpr int OFF_CNT = 3703696;  // [2][128] int receiver-degree
constexpr int OFF_LST = 3703952;  // [2][128][64] int edge lists

// mirror sub-offsets (within mirror; dist removed, later entries shifted)
#define M_NODES1 (mir + 0)
#define M_EDGES1 (mir + 2048)
#define M_NODES2 (mir + 6144)
#define M_EDGES2 (mir + 8192)
#define M_C1     (mir + 12288)
#define M_C2     (mir + 36864)
#define M_MP     (mir + 61440)
#define M_WEN    (mir + 77824)
#define M_BEN    (mir + 78848)
#define M_WEE    (mir + 78912)
#define M_BEE    (mir + 79424)
#define M_WGE    (mir + 79488)
#define M_BGE    (mir + 116352)
#define M_WGN    (mir + 116544)
#define M_BGN    (mir + 141120)
#define M_PPW0   (mir + 141312)
#define M_PPB0   (mir + 149504)
#define M_PPW1   (mir + 149568)
#define M_PPB1   (mir + 153664)
#define M_PPW2   (mir + 153728)
#define M_PPB2   (mir + 154048)
#define M_APW0   (mir + 154053)
#define M_APB0   (mir + 158149)
#define M_APW1   (mir + 158213)
#define M_APB1   (mir + 162309)
#define M_APW2   (mir + 162373)
#define M_APB2   (mir + 162693)

__constant__ int c_moff[28] = {0,2048,6144,8192,12288,36864,61440,77824,
  78848,78912,79424,79488,116352,116544,141120,141312,149504,149568,
  153664,153728,154048,154053,158149,158213,162309,162373,162693,162698};
__constant__ int c_mcnt[27] = {2048,4096,2048,4096,24576,24576,16384,
  1024,64,512,64,36864,192,24576,192,8192,64,4096,64,320,5,4096,64,4096,64,320,5};

// ---- convert + probe + PAR/ACC zero + FLAG + build lists (one kernel) ----
__global__ void __launch_bounds__(256) k_convert(
    const void* s0, const void* s1, const void* s2, const void* s3,
    const void* s4, const void* s5, const void* s6, const void* s7,
    const void* s8, const void* s9, const void* s10, const void* s11,
    const void* s12, const void* s13, const void* s14, const void* s15,
    const void* s16, const void* s17, const void* s18, const void* s19,
    const void* s20, const void* s21, const void* s22, const void* s23,
    const void* s24, const void* s25, const void* s26,
    const void* distraw, const int* recv1, const int* recv2, float* ws)
{
  __shared__ int sflag;
  __shared__ int bcnt[128];
  int t = threadIdx.x, bid = blockIdx.x;
  if (t < 64) {
    float v = b2f(((const unsigned short*)distraw)[t]);
    bool ok = (v > 0.25f) && (v < 512.f);
    unsigned long long m = __ballot(ok);
    if (t == 0) sflag = (m == ~0ull) ? 1 : 0;
  }
  __syncthreads();
  bool isbf = sflag != 0;
  if (bid < 636) {
    const void* sp[27] = {s0,s1,s2,s3,s4,s5,s6,s7,s8,s9,s10,s11,s12,s13,
                          s14,s15,s16,s17,s18,s19,s20,s21,s22,s23,s24,s25,s26};
    int g = bid*256 + t;
    if (g >= MTOT) return;
    int lo = 0, hi = 27;
    #pragma unroll
    for (int st = 0; st < 5; st++) {
      int mid = (lo + hi) >> 1;
      if (g >= c_moff[mid]) lo = mid; else hi = mid;
    }
    int local = g - c_moff[lo];
    if (local < c_mcnt[lo]) {
      float v = isbf ? b2f(((const unsigned short*)sp[lo])[local])
                     : ((const float*)sp[lo])[local];
      ws[OFF_MIR + g] = v;
    }
  } else if (bid < 956) {
    ws[OFF_PAR + (bid-636)*256 + t] = 0.f;    // 320*256 = 81920 exactly
  } else if (bid == 956) {
    ws[OFF_ACC + t] = 0.f;
    if (t == 0) ws[OFF_FLAG] = isbf ? 1.f : 0.f;
  } else {
    int g = bid - 957;                         // 0 or 1
    const int* recv = g ? recv2 : recv1;
    if (t < 128) bcnt[t] = 0;
    __syncthreads();
    for (int pass = 0; pass < 2; pass++) {
      int ed = pass*256 + t;
      int nd = recv[ed];
      int pos = atomicAdd(&bcnt[nd], 1);
      if (pos < 64) ((int*)ws)[OFF_LST + (g*128+nd)*64 + pos] = ed;
    }
    __syncthreads();
    if (t < 128) ((int*)ws)[OFF_CNT + g*128 + t] = bcnt[t];
  }
}

// ---------------- GNN embeddings ----------------
__global__ void __launch_bounds__(256) k_emb(float* ws)
{
  const float* mir = ws + OFF_MIR;
  int t = threadIdx.x, c = t & 63;
  int row = blockIdx.x * 4 + (t >> 6);       // 0..1279
  if (row < 256) {
    int g = row >> 7, nd = row & 127;
    const float* src = g ? M_NODES2 : M_NODES1;
    float acc = M_BEN[c];
    for (int k = 0; k < 16; k++) acc += src[nd*16+k] * M_WEN[k*64+c];
    ws[OFF_N + (g*128+nd)*64 + c] = mila(acc);
  } else {
    int er = row - 256; int g = er >> 9, ed = er & 511;
    const float* src = g ? M_EDGES2 : M_EDGES1;
    float acc = M_BEE[c];
    for (int k = 0; k < 8; k++) acc += src[ed*8+k] * M_WEE[k*64+c];
    ws[OFF_E + (g*512+ed)*64 + c] = mila(acc);
  }
}

// ---------------- GNN edge update (step s) ----------------
__global__ void __launch_bounds__(256) k_edge(const int* recv1, const int* send1,
    const int* recv2, const int* send2, int s, float* ws)
{
  const float* mir = ws + OFF_MIR;
  __shared__ float ein[4][192];
  int t = threadIdx.x;
  int le = t >> 6, c = t & 63;
  int eidx = blockIdx.x * 4;                 // among 1024 edge-rows (2 graphs)
  const float* n = ws + OFF_N;
  const float* e = ws + OFF_E;
  for (int q = t; q < 768; q += 256) {
    int ee = q / 192, k = q % 192;
    int ge = eidx + ee; int g = ge >> 9, ed = ge & 511;
    const int* recv = g ? recv2 : recv1;
    const int* send = g ? send2 : send1;
    float v;
    if (k < 64)       v = e[(g*512+ed)*64 + k];
    else if (k < 128) v = n[(g*128+recv[ed])*64 + (k-64)];
    else              v = n[(g*128+send[ed])*64 + (k-128)];
    ein[ee][k] = v;
  }
  __syncthreads();
  const float* W = M_WGE + s*192*64;
  float acc = M_BGE[s*64+c];
  for (int k = 0; k < 192; k++) acc += ein[le][k] * W[k*64+c];
  int ge = eidx + le; int g = ge >> 9, ed = ge & 511;
  ws[OFF_E + (g*512+ed)*64 + c] = mila(acc);   // in-place: block owns its 4 rows
}

// ---------------- GNN node update (step s): list gather ----------------
__global__ void __launch_bounds__(64) k_node(const int* recv1, const int* recv2,
    int s, float* ws)
{
  const float* mir = ws + OFF_MIR;
  __shared__ float xin[128];
  int c = threadIdx.x;
  int g = blockIdx.x >> 7, nd = blockIdx.x & 127;
  const float* n = ws + OFF_N;
  const float* e = ws + OFF_E;
  int cnt = ((const int*)ws)[OFF_CNT + g*128 + nd];
  float agg = 0.f;
  if (cnt <= 64) {
    const int* lst = (const int*)ws + OFF_LST + (g*128+nd)*64;
    for (int q = 0; q < cnt; q++) {
      int ed = lst[q];                      // wave-uniform
      agg += e[(g*512+ed)*64 + c];
    }
  } else {                                  // safety fallback (degree > 64)
    const int* recv = g ? recv2 : recv1;
    for (int ed = 0; ed < 512; ed++)
      if (recv[ed] == nd) agg += e[(g*512+ed)*64 + c];
  }
  xin[c] = n[(g*128+nd)*64 + c];
  xin[64 + c] = agg;
  __syncthreads();
  const float* W = M_WGN + s*128*64;
  float acc = M_BGN[s*64+c];
  for (int k = 0; k < 128; k++) acc += xin[k] * W[k*64+c];
  ws[OFF_N + (g*128+nd)*64 + c] = mila(acc);   // in-place: block owns row nd
}

// ---------------- tables A1/A2/B1/B2 + ap MLPs + h-mask ----------------
__global__ void __launch_bounds__(256) k_prep(float* ws)
{
  const float* mir = ws + OFF_MIR;
  __shared__ float sh[4][64], sh2[4][64];
  int t = threadIdx.x;
  const float* n = ws + OFF_N;
  if (blockIdx.x < 128) {
    int T = blockIdx.x >> 5, rg = blockIdx.x & 31;
    int r = rg*4 + (t >> 6), c = t & 63;
    const float* f = (T == 0 || T == 2) ? n : (n + 128*64);
    int wofs = (T == 0 || T == 3) ? 0 : 64;
    float acc = (T == 1 || T == 2) ? M_PPB0[c] : 0.f;
    for (int k = 0; k < 64; k++) acc += f[r*64+k] * M_PPW0[(wofs+k)*64 + c];
    if (T == 0)      ws[OFF_A1 + r*64 + c] = acc;
    else if (T == 1) ws[OFF_A2 + c*128 + r] = acc;
    else if (T == 2) ws[OFF_B1 + r*64 + c] = acc;
    else             ws[OFF_B2 + c*128 + r] = acc;
  } else {
    int b2i = blockIdx.x - 128;
    int g = b2i >> 5, grp = b2i & 31;
    int ln = t >> 6, c = t & 63;
    int nd = grp*4 + ln;
    const float* f = n + (g*128+nd)*64;
    float acc = M_APB0[c];
    for (int k = 0; k < 64; k++) acc += f[k] * M_APW0[k*64+c];
    sh[ln][c] = mila(acc);
    __syncthreads();
    acc = M_APB1[c];
    for (int k = 0; k < 64; k++) acc += sh[ln][k] * M_APW1[k*64+c];
    sh2[ln][c] = mila(acc);
    __syncthreads();
    if (c < 5) {
      float a2 = M_APB2[c];
      for (int k = 0; k < 64; k++) a2 += sh2[ln][k] * M_APW2[k*5+c];
      ws[OFF_APT + (g*5+c)*128 + nd] = ssp_(a2);
    }
    if (c == 0) {
      const float* ns = (g ? M_NODES2 : M_NODES1) + nd*16;
      float v0 = ns[0];
      float ok = 1.f;
      for (int k = 1; k < 16; k++) if (ns[k] > v0) ok = 0.f;
      ws[OFF_HM + g*128 + nd] = ok;
    }
  }
}

// ---------------- pair MLP v3: 512 blocks x 256 threads ----------------
__global__ void __launch_bounds__(256) k_pair(float* ws)
{
  const float* mir = ws + OFF_MIR;
  float* params = ws + OFF_PAR;
  __shared__ float W1s[4096];     // [c][o]
  __shared__ float W2s[320];      // [k][o5]
  __shared__ float b1s[64], b2s[8], bases[64];
  __shared__ float h0s[4096];     // [c][jl] 64x64
  __shared__ float opart[64][4][5];
  int t = threadIdx.x;
  int jl = t & 63, h = t >> 6;
  int i = blockIdx.x >> 2, dir = (blockIdx.x >> 1) & 1, jh = blockIdx.x & 1;
  const float* base = ws + (dir ? OFF_B1 : OFF_A1) + i*64;
  const float* oT   = ws + (dir ? OFF_B2 : OFF_A2) + jh*64;
  #pragma unroll
  for (int q = 0; q < 16; q++) W1s[q*256 + t] = M_PPW1[q*256 + t];
  for (int q = t; q < 320; q += 256) W2s[q] = M_PPW2[q];
  if (t < 64) { b1s[t] = M_PPB1[t]; bases[t] = base[t]; }
  if (t >= 64 && t < 72) b2s[t-64] = (t-64 < 5) ? M_PPB2[t-64] : 0.f;
  __syncthreads();
  #pragma unroll
  for (int q = 0; q < 16; q++) {
    int idx = q*256 + t;
    int c = idx >> 6, j2 = idx & 63;
    h0s[idx] = mila(bases[c] + oT[c*128 + j2]);
  }
  __syncthreads();
  float h1c[16];
  #pragma unroll
  for (int k = 0; k < 16; k++) h1c[k] = b1s[h*16 + k];
  for (int c = 0; c < 64; c++) {
    float h0c = h0s[c*64 + jl];
    const float4* w4 = (const float4*)&W1s[c*64 + h*16];
    float4 wa = w4[0], wb = w4[1], wc = w4[2], wd = w4[3];
    h1c[0]  += h0c*wa.x; h1c[1]  += h0c*wa.y; h1c[2]  += h0c*wa.z; h1c[3]  += h0c*wa.w;
    h1c[4]  += h0c*wb.x; h1c[5]  += h0c*wb.y; h1c[6]  += h0c*wb.z; h1c[7]  += h0c*wb.w;
    h1c[8]  += h0c*wc.x; h1c[9]  += h0c*wc.y; h1c[10] += h0c*wc.z; h1c[11] += h0c*wc.w;
    h1c[12] += h0c*wd.x; h1c[13] += h0c*wd.y; h1c[14] += h0c*wd.z; h1c[15] += h0c*wd.w;
  }
  float o5p[5] = {0.f, 0.f, 0.f, 0.f, 0.f};
  #pragma unroll
  for (int k = 0; k < 16; k++) {
    float hk = mila(h1c[k]);
    int kk = h*16 + k;
    #pragma unroll
    for (int o = 0; o < 5; o++) o5p[o] += hk * W2s[kk*5 + o];
  }
  #pragma unroll
  for (int o = 0; o < 5; o++) opart[jl][h][o] = o5p[o];
  __syncthreads();
  if (t < 64) {
    int p = i*128 + jh*64 + t;
    #pragma unroll
    for (int o = 0; o < 5; o++) {
      float val = b2s[o] + opart[t][0][o] + opart[t][1][o]
                         + opart[t][2][o] + opart[t][3][o];
      atomicAdd(&params[p*5 + o], ssp_(val));
    }
  }
}

// ======== induction v5: 64 blocks x 1024 threads, pass-split ==========
// E0 phases: 1 row(col)/thread, il = t>>3 in [0,128), sub = t&7.
// Iterations: waves 0-7 (t<512) compute f1 (pass A), waves 8-15 compute f2
// (pass B) CONCURRENTLY (Jacobi reads only old m1/m2). Each group: il2 in
// [0,64) owns rows/cols {il2, il2+64}; iteration-invariant coords (c2s[j]
// for A, c1s[i] for B) hoisted into 48 VGPRs -> per-iter LDS is just c35
// b64 reads + one m-vector b128 + shfl. 16 waves/CU for latency hiding.
__global__ void __launch_bounds__(1024) k_ind_all(const void* distp, float* ws)
{
  const float* mir = ws + OFF_MIR;
  const float* apT = ws + OFF_APT;
  __shared__ __align__(8) float2 sC35[128*132];
  __shared__ float4 c1s[128], c2s[128], m1s[128], m2s[128];
  __shared__ float4 e01s[128], e02s[128], f1s[128], f2s[128];
  __shared__ float p1s[128], p2s[128], q1s[128], q2s[128];
  __shared__ float esum[128];
  int b = blockIdx.x, t = threadIdx.x;
  bool isbf = ws[OFF_FLAG] != 0.f;
  if (t < 128) {
    c1s[t] = make_float4(M_C1[(b*128+t)*3], M_C1[(b*128+t)*3+1], M_C1[(b*128+t)*3+2], 0.f);
    c2s[t] = make_float4(M_C2[(b*128+t)*3], M_C2[(b*128+t)*3+1], M_C2[(b*128+t)*3+2], 0.f);
    p1s[t] = apT[128 + t];
    p2s[t] = apT[(5+1)*128 + t];
    q1s[t] = M_MP[b*128 + t];
    q2s[t] = M_MP[8192 + b*128 + t];
  }
  __syncthreads();
  int il = t >> 3, sub = t & 7;
  // phase 1: c35 table + E0_1 row sums (1 row/thread, all 1024 threads)
  {
    float4 c1 = c1s[il];
    float p1 = p1s[il];
    float ex = 0, ey = 0, ez = 0;
    #pragma unroll 4
    for (int jj = 0; jj < 16; jj++) {
      int j = sub + 8*jj;
      float R = rdist(distp, (long)b*16384 + il*128 + j, isbf);
      float R2 = R*R, R3 = R2*R, R5 = R3*R2;
      float au = sqrtf(p1 * p2s[j]) + 1e-6f;
      float u3 = R3 / au;
      float exu = expf(-0.39f * u3);
      float c3 = (1.f - exu) / (R3 + 1e-6f);
      float c5 = 3.f * (1.f - (1.f + 0.39f*u3) * exu) / (R5 + 1e-6f);
      sC35[il*132 + j] = make_float2(c3, c5);
      float w = q2s[j] * c3;
      ex += w*(c1.x - c2s[j].x); ey += w*(c1.y - c2s[j].y); ez += w*(c1.z - c2s[j].z);
    }
    #pragma unroll
    for (int m = 1; m <= 4; m <<= 1) {
      ex += __shfl_xor(ex, m, 64); ey += __shfl_xor(ey, m, 64); ez += __shfl_xor(ez, m, 64);
    }
    if (sub == 0) e01s[il] = make_float4(ex, ey, ez, 0.f);
  }
  __syncthreads();
  // phase 2: E0_2 col sums (1 col/thread)
  {
    float4 c2 = c2s[il];
    float ex = 0, ey = 0, ez = 0;
    #pragma unroll 4
    for (int jj = 0; jj < 16; jj++) {
      int i = sub + 8*jj;
      float c3 = sC35[i*132 + il].x;
      float w = q1s[i] * c3;
      ex -= w*(c1s[i].x - c2.x); ey -= w*(c1s[i].y - c2.y); ez -= w*(c1s[i].z - c2.z);
    }
    #pragma unroll
    for (int m = 1; m <= 4; m <<= 1) {
      ex += __shfl_xor(ex, m, 64); ey += __shfl_xor(ey, m, 64); ez += __shfl_xor(ez, m, 64);
    }
    if (sub == 0) e02s[il] = make_float4(ex, ey, ez, 0.f);
  }
  __syncthreads();
  if (t < 128) {
    float4 e1 = e01s[t], e2 = e02s[t];
    m1s[t] = make_float4(p1s[t]*e1.x, p1s[t]*e1.y, p1s[t]*e1.z, 0.f);
    m2s[t] = make_float4(p2s[t]*e2.x, p2s[t]*e2.y, p2s[t]*e2.z, 0.f);
  }
  __syncthreads();
  // iteration groups: grp 0 (t<512) = pass A (f1), grp 1 = pass B (f2)
  int grp = t >> 9;
  int tl = t & 511;
  int il2 = tl >> 3, sub2 = tl & 7;
  int r0 = il2, r1 = il2 + 64;
  // hoist iteration-invariant partner coords (wave-uniform branch)
  float hx[16], hy[16], hz[16];
  #pragma unroll
  for (int jj = 0; jj < 16; jj++) {
    int o = sub2 + 8*jj;
    float4 v = grp ? c1s[o] : c2s[o];
    hx[jj] = v.x; hy[jj] = v.y; hz[jj] = v.z;
  }
  float4 cA = grp ? c2s[r0] : c1s[r0];
  float4 cB = grp ? c2s[r1] : c1s[r1];
  // 8 Jacobi iterations
  for (int it = 0; it < 8; it++) {
    float fax = 0, fay = 0, faz = 0, fbx = 0, fby = 0, fbz = 0;
    if (grp == 0) {
      // f1[r0], f1[r1]: sum_j c5*(r.m2)*r - c3*m2, r = c1[row] - c2[j]
      #pragma unroll
      for (int jj = 0; jj < 16; jj++) {
        int j = sub2 + 8*jj;
        float2 cca = sC35[r0*132 + j];
        float2 ccb = sC35[r1*132 + j];
        float4 m2 = m2s[j];
        {
          float rx = cA.x - hx[jj], ry = cA.y - hy[jj], rz = cA.z - hz[jj];
          float dot = rx*m2.x + ry*m2.y + rz*m2.z;
          float a = cca.y * dot;
          fax += a*rx - cca.x*m2.x; fay += a*ry - cca.x*m2.y; faz += a*rz - cca.x*m2.z;
        }
        {
          float rx = cB.x - hx[jj], ry = cB.y - hy[jj], rz = cB.z - hz[jj];
          float dot = rx*m2.x + ry*m2.y + rz*m2.z;
          float a = ccb.y * dot;
          fbx += a*rx - ccb.x*m2.x; fby += a*ry - ccb.x*m2.y; fbz += a*rz - ccb.x*m2.z;
        }
      }
    } else {
      // f2[r0], f2[r1]: sum_i c5*(r.m1)*r - c3*m1, r = c1[i] - c2[col]
      #pragma unroll
      for (int jj = 0; jj < 16; jj++) {
        int i = sub2 + 8*jj;
        float2 cca = sC35[i*132 + r0];
        float2 ccb = sC35[i*132 + r1];
        float4 m1 = m1s[i];
        {
          float rx = hx[jj] - cA.x, ry = hy[jj] - cA.y, rz = hz[jj] - cA.z;
          float dot = rx*m1.x + ry*m1.y + rz*m1.z;
          float a = cca.y * dot;
          fax += a*rx - cca.x*m1.x; fay += a*ry - cca.x*m1.y; faz += a*rz - cca.x*m1.z;
        }
        {
          float rx = hx[jj] - cB.x, ry = hy[jj] - cB.y, rz = hz[jj] - cB.z;
          float dot = rx*m1.x + ry*m1.y + rz*m1.z;
          float a = ccb.y * dot;
          fbx += a*rx - ccb.x*m1.x; fby += a*ry - ccb.x*m1.y; fbz += a*rz - ccb.x*m1.z;
        }
      }
    }
    #pragma unroll
    for (int m = 1; m <= 4; m <<= 1) {
      fax += __shfl_xor(fax, m, 64); fay += __shfl_xor(fay, m, 64); faz += __shfl_xor(faz, m, 64);
      fbx += __shfl_xor(fbx, m, 64); fby += __shfl_xor(fby, m, 64); fbz += __shfl_xor(fbz, m, 64);
    }
    if (sub2 == 0) {
      if (grp == 0) {
        f1s[r0] = make_float4(fax, fay, faz, 0.f);
        f1s[r1] = make_float4(fbx, fby, fbz, 0.f);
      } else {
        f2s[r0] = make_float4(fax, fay, faz, 0.f);
        f2s[r1] = make_float4(fbx, fby, fbz, 0.f);
      }
    }
    __syncthreads();
    if (t < 128) {
      float4 f1 = f1s[t], e1 = e01s[t], mo1 = m1s[t];
      float4 f2 = f2s[t], e2 = e02s[t], mo2 = m2s[t];
      float p1 = p1s[t], p2 = p2s[t];
      m1s[t] = make_float4(0.25f*mo1.x + 0.75f*p1*(e1.x + f1.x),
                           0.25f*mo1.y + 0.75f*p1*(e1.y + f1.y),
                           0.25f*mo1.z + 0.75f*p1*(e1.z + f1.z), 0.f);
      m2s[t] = make_float4(0.25f*mo2.x + 0.75f*p2*(e2.x + f2.x),
                           0.25f*mo2.y + 0.75f*p2*(e2.y + f2.y),
                           0.25f*mo2.z + 0.75f*p2*(e2.z + f2.z), 0.f);
    }
    __syncthreads();
  }
  // energy + mu store
  if (t < 128) {
    float4 m1 = m1s[t], m2 = m2s[t], e1 = e01s[t], e2 = e02s[t];
    esum[t] = m1.x*e1.x + m1.y*e1.y + m1.z*e1.z
            + m2.x*e2.x + m2.y*e2.y + m2.z*e2.z;
    *(float4*)&ws[OFF_MU1 + (b*128+t)*4] = m1;
    *(float4*)&ws[OFF_MU2 + (b*128+t)*4] = m2;
  }
  __syncthreads();
  if (t == 0) {
    float s = 0.f;
    for (int k = 0; k < 128; k++) s += esum[k];
    ws[OFF_ACC + 64 + b] = -0.5f * s;     // ct subtracted by k_terms
  }
}

// ---------------- es / ex / disp / ct terms: 1024 blocks ----------------
__global__ void __launch_bounds__(256) k_terms(const void* distp, float* ws)
{
  const float* mir = ws + OFF_MIR;
  int b = blockIdx.x >> 4, q = blockIdx.x & 15;
  int t = threadIdx.x;
  bool isbf = ws[OFF_FLAG] != 0.f;
  const float* par = ws + OFF_PAR;
  const float* apT = ws + OFF_APT;
  const float* hm  = ws + OFF_HM;
  const float* mu1 = ws + OFF_MU1;
  const float* mu2 = ws + OFF_MU2;
  float es = 0, ct = 0, ex = 0, dp = 0;
  for (int s = 0; s < 4; s++) {
    int p = q*1024 + s*256 + t;
    int i = p >> 7, j = p & 127;
    float C6 = par[p*5+0], C8 = par[p*5+1], C10 = par[p*5+2];
    float Act = par[p*5+3], bct = par[p*5+4];
    float R = rdist(distp, (long)b*16384 + p, isbf);
    float Rs = R + 1e-6f;
    float B0 = 1.f / Rs;
    float R2 = R*R;
    float R6 = R2*R2*R2, R8 = R6*R2, R10 = R8*R2;
    float r0 = C8 / (C6 + 1e-6f);
    float D6 = r0*r0*r0, D8 = D6*r0, D10 = D8*r0;
    if (R2 < 2500.f) dp -= C6/(R6+D6) + C8/(R8+D8) + C10/(R10+D10);
    ct += Act * expf(-bct * R);
    float q1v = M_MP[b*128 + i];
    float q2v = M_MP[8192 + b*128 + j];
    float ad1 = apT[0*128 + i],   ad2 = apT[(5+0)*128 + j];
    float k1v = apT[2*128 + i],   k2v = apT[(5+2)*128 + j];
    float ae1 = apT[4*128 + i],   ae2 = apT[(5+4)*128 + j];
    float dq1 = apT[3*128 + i],   dq2 = apT[(5+3)*128 + j];
    float bd = sqrtf(ad1*ad2), be = sqrtf(ae1*ae2), Kp = k1v*k2v;
    float ebd = expf(-bd * R);
    float fd = 1.f - (1.f + 0.5f*bd*R) * ebd;
    es += q1v * q2v * fd * B0;
    float rxx = M_C2[(b*128+j)*3+0] - M_C1[(b*128+i)*3+0];
    float rxy = M_C2[(b*128+j)*3+1] - M_C1[(b*128+i)*3+1];
    float rxz = M_C2[(b*128+j)*3+2] - M_C1[(b*128+i)*3+2];
    float m1x = mu1[(b*128+i)*4+0], m1y = mu1[(b*128+i)*4+1], m1z = mu1[(b*128+i)*4+2];
    float m2x = mu2[(b*128+j)*4+0], m2y = mu2[(b*128+j)*4+1], m2z = mu2[(b*128+j)*4+2];
    float proj = ((m1x-m2x)*rxx + (m1y-m2y)*rxy + (m1z-m2z)*rxz) * B0;
    float h1v = hm[i], h2v = hm[128 + j];
    float qe1 = h1v > 0.5f ? (1.f - q1v) : (2.f + dq1 - q1v);
    float qe2 = h2v > 0.5f ? (1.f - q2v) : (2.f + dq2 - q2v);
    ex += Kp * qe1 * qe2 * (1.f + proj) * expf(-be * R) * B0;
  }
  __shared__ float sred[4][4];
  for (int m = 32; m >= 1; m >>= 1) {
    es += __shfl_xor(es, m, 64); ct += __shfl_xor(ct, m, 64);
    ex += __shfl_xor(ex, m, 64); dp += __shfl_xor(dp, m, 64);
  }
  int w = t >> 6;
  if ((t & 63) == 0) { sred[w][0] = es; sred[w][1] = ct; sred[w][2] = ex; sred[w][3] = dp; }
  __syncthreads();
  if (t == 0) {
    float a0 = 0, a1 = 0, a2 = 0, a3 = 0;
    for (int ww = 0; ww < 4; ww++) { a0 += sred[ww][0]; a1 += sred[ww][1]; a2 += sred[ww][2]; a3 += sred[ww][3]; }
    atomicAdd(&ws[OFF_ACC +   0 + b], a0);   // es
    atomicAdd(&ws[OFF_ACC +  64 + b], -a1);  // in -= ct
    atomicAdd(&ws[OFF_ACC + 128 + b], a2);   // ex
    atomicAdd(&ws[OFF_ACC + 192 + b], a3);   // disp
  }
}

// ---------------- finalize: total + dtype-matched output ----------------
__global__ void __launch_bounds__(64) k_total(const float* ws, void* outv)
{
  int b = threadIdx.x;
  float es  = ws[OFF_ACC +   0 + b];
  float inv = ws[OFF_ACC +  64 + b];
  float ex  = ws[OFF_ACC + 128 + b];
  float dp  = ws[OFF_ACC + 192 + b];
  float tot = ex + dp + es + inv;
  if (ws[OFF_FLAG] != 0.f) {
    unsigned short* out = (unsigned short*)outv;
    out[b]       = f2b(tot);
    out[64 + b]  = f2b(es);
    out[128 + b] = f2b(inv);
    out[192 + b] = f2b(ex);
    out[256 + b] = f2b(dp);
  } else {
    float* out = (float*)outv;
    out[b]       = tot;
    out[64 + b]  = es;
    out[128 + b] = inv;
    out[192 + b] = ex;
    out[256 + b] = dp;
  }
}

extern "C" void kernel_launch(void* const* d_in, const int* in_sizes, int n_in,
                              void* d_out, int out_size, void* d_ws, size_t ws_size,
                              hipStream_t stream)
{
  const int* send1 = (const int*)d_in[2];
  const int* recv1 = (const int*)d_in[3];
  const int* send2 = (const int*)d_in[6];
  const int* recv2 = (const int*)d_in[7];
  float* ws = (float*)d_ws;

  k_convert<<<959, 256, 0, stream>>>(
      d_in[0], d_in[1], d_in[4], d_in[5], d_in[8], d_in[9], d_in[11],
      d_in[12], d_in[13], d_in[14], d_in[15], d_in[16], d_in[17], d_in[18],
      d_in[19], d_in[20], d_in[21], d_in[22], d_in[23], d_in[24], d_in[25],
      d_in[26], d_in[27], d_in[28], d_in[29], d_in[30], d_in[31],
      d_in[10], recv1, recv2, ws);

  k_emb<<<320, 256, 0, stream>>>(ws);
  for (int s = 0; s < 3; s++) {
    k_edge<<<256, 256, 0, stream>>>(recv1, send1, recv2, send2, s, ws);
    k_node<<<256, 64, 0, stream>>>(recv1, recv2, s, ws);
  }
  k_prep<<<192, 256, 0, stream>>>(ws);
  k_pair<<<512, 256, 0, stream>>>(ws);
  k_ind_all<<<64, 1024, 0, stream>>>(d_in[10], ws);
  k_terms<<<1024, 256, 0, stream>>>(d_in[10], ws);
  k_total<<<1, 64, 0, stream>>>(ws, d_out);
}

// Round 14
// 280.352 us; speedup vs baseline: 1.4210x; 1.4210x over previous
//
#include <hip/hip_runtime.h>

#define DEVI __device__ __forceinline__

DEVI float b2f(unsigned short u){
  union { unsigned u; float f; } v; v.u = ((unsigned)u) << 16; return v.f;
}
DEVI unsigned short f2b(float f){
  union { float f; unsigned u; } v; v.f = f;
  unsigned r = (v.u + 0x7fffu + ((v.u >> 16) & 1u)) >> 16;
  return (unsigned short)r;
}
// jax.nn.softplus(x) = max(x,0) + log1p(exp(-|x|))
DEVI float splus(float x){ return fmaxf(x, 0.f) + log1pf(expf(-fabsf(x))); }
DEVI float mila(float x){ return x * tanhf(splus(x - 1.f)); }
DEVI float ssp_(float x){ return splus(x) + 0.001f; }
// dist accessor: raw input, bf16 or f32 per flag
DEVI float rdist(const void* p, long idx, bool isbf){
  return isbf ? b2f(((const unsigned short*)p)[idx]) : ((const float*)p)[idx];
}

// ---------------- workspace layout (float elements) ----------------
constexpr int OFF_N   = 0;        // feats/nodes [2][128][64]
constexpr int OFF_E   = 16384;    // edges [2][512][64]
constexpr int OFF_A1  = 81920;    // [128][64]  f1 @ W0[0:64]
constexpr int OFF_A2  = 90112;    // [64][128]T f2 @ W0[64:128] + b0
constexpr int OFF_B1  = 98304;    // [128][64]  f1 @ W0[64:128] + b0
constexpr int OFF_B2  = 106496;   // [64][128]T f2 @ W0[0:64]
constexpr int OFF_APT = 114688;   // [2][5][128] ap outputs, transposed
constexpr int OFF_HM  = 115968;   // [2][128] argmax==0 mask
constexpr int OFF_PAR = 116224;   // [16384][5] pair params (atomically summed)
constexpr int OFF_MU1 = 198144;   // [64][128][4]
constexpr int OFF_MU2 = 230912;   // [64][128][4]
constexpr int OFF_ACC = 263680;   // [4][64]: es, in, ex, disp
constexpr int OFF_FLAG= 263936;   // 1.0 if inputs bf16, 0.0 if f32
constexpr int OFF_MIR = 264192;   // f32 mirror of all float inputs EXCEPT dist
constexpr int MTOT    = 162698;   // mirror size (dist excluded)
constexpr int OFF_CNT = 3703696;  // [2][128] int receiver-degree
constexpr int OFF_LST = 3703952;  // [2][128][64] int edge lists

// mirror sub-offsets (within mirror; dist removed, later entries shifted)
#define M_NODES1 (mir + 0)
#define M_EDGES1 (mir + 2048)
#define M_NODES2 (mir + 6144)
#define M_EDGES2 (mir + 8192)
#define M_C1     (mir + 12288)
#define M_C2     (mir + 36864)
#define M_MP     (mir + 61440)
#define M_WEN    (mir + 77824)
#define M_BEN    (mir + 78848)
#define M_WEE    (mir + 78912)
#define M_BEE    (mir + 79424)
#define M_WGE    (mir + 79488)
#define M_BGE    (mir + 116352)
#define M_WGN    (mir + 116544)
#define M_BGN    (mir + 141120)
#define M_PPW0   (mir + 141312)
#define M_PPB0   (mir + 149504)
#define M_PPW1   (mir + 149568)
#define M_PPB1   (mir + 153664)
#define M_PPW2   (mir + 153728)
#define M_PPB2   (mir + 154048)
#define M_APW0   (mir + 154053)
#define M_APB0   (mir + 158149)
#define M_APW1   (mir + 158213)
#define M_APB1   (mir + 162309)
#define M_APW2   (mir + 162373)
#define M_APB2   (mir + 162693)

__constant__ int c_moff[28] = {0,2048,6144,8192,12288,36864,61440,77824,
  78848,78912,79424,79488,116352,116544,141120,141312,149504,149568,
  153664,153728,154048,154053,158149,158213,162309,162373,162693,162698};
__constant__ int c_mcnt[27] = {2048,4096,2048,4096,24576,24576,16384,
  1024,64,512,64,36864,192,24576,192,8192,64,4096,64,320,5,4096,64,4096,64,320,5};

// ---- convert + probe + PAR/ACC zero + FLAG + build lists (one kernel) ----
__global__ void __launch_bounds__(256) k_convert(
    const void* s0, const void* s1, const void* s2, const void* s3,
    const void* s4, const void* s5, const void* s6, const void* s7,
    const void* s8, const void* s9, const void* s10, const void* s11,
    const void* s12, const void* s13, const void* s14, const void* s15,
    const void* s16, const void* s17, const void* s18, const void* s19,
    const void* s20, const void* s21, const void* s22, const void* s23,
    const void* s24, const void* s25, const void* s26,
    const void* distraw, const int* recv1, const int* recv2, float* ws)
{
  __shared__ int sflag;
  __shared__ int bcnt[128];
  int t = threadIdx.x, bid = blockIdx.x;
  if (t < 64) {
    float v = b2f(((const unsigned short*)distraw)[t]);
    bool ok = (v > 0.25f) && (v < 512.f);
    unsigned long long m = __ballot(ok);
    if (t == 0) sflag = (m == ~0ull) ? 1 : 0;
  }
  __syncthreads();
  bool isbf = sflag != 0;
  if (bid < 636) {
    const void* sp[27] = {s0,s1,s2,s3,s4,s5,s6,s7,s8,s9,s10,s11,s12,s13,
                          s14,s15,s16,s17,s18,s19,s20,s21,s22,s23,s24,s25,s26};
    int g = bid*256 + t;
    if (g >= MTOT) return;
    int lo = 0, hi = 27;
    #pragma unroll
    for (int st = 0; st < 5; st++) {
      int mid = (lo + hi) >> 1;
      if (g >= c_moff[mid]) lo = mid; else hi = mid;
    }
    int local = g - c_moff[lo];
    if (local < c_mcnt[lo]) {
      float v = isbf ? b2f(((const unsigned short*)sp[lo])[local])
                     : ((const float*)sp[lo])[local];
      ws[OFF_MIR + g] = v;
    }
  } else if (bid < 956) {
    ws[OFF_PAR + (bid-636)*256 + t] = 0.f;    // 320*256 = 81920 exactly
  } else if (bid == 956) {
    ws[OFF_ACC + t] = 0.f;
    if (t == 0) ws[OFF_FLAG] = isbf ? 1.f : 0.f;
  } else {
    int g = bid - 957;                         // 0 or 1
    const int* recv = g ? recv2 : recv1;
    if (t < 128) bcnt[t] = 0;
    __syncthreads();
    for (int pass = 0; pass < 2; pass++) {
      int ed = pass*256 + t;
      int nd = recv[ed];
      int pos = atomicAdd(&bcnt[nd], 1);
      if (pos < 64) ((int*)ws)[OFF_LST + (g*128+nd)*64 + pos] = ed;
    }
    __syncthreads();
    if (t < 128) ((int*)ws)[OFF_CNT + g*128 + t] = bcnt[t];
  }
}

// ---------------- GNN embeddings ----------------
__global__ void __launch_bounds__(256) k_emb(float* ws)
{
  const float* mir = ws + OFF_MIR;
  int t = threadIdx.x, c = t & 63;
  int row = blockIdx.x * 4 + (t >> 6);       // 0..1279
  if (row < 256) {
    int g = row >> 7, nd = row & 127;
    const float* src = g ? M_NODES2 : M_NODES1;
    float acc = M_BEN[c];
    for (int k = 0; k < 16; k++) acc += src[nd*16+k] * M_WEN[k*64+c];
    ws[OFF_N + (g*128+nd)*64 + c] = mila(acc);
  } else {
    int er = row - 256; int g = er >> 9, ed = er & 511;
    const float* src = g ? M_EDGES2 : M_EDGES1;
    float acc = M_BEE[c];
    for (int k = 0; k < 8; k++) acc += src[ed*8+k] * M_WEE[k*64+c];
    ws[OFF_E + (g*512+ed)*64 + c] = mila(acc);
  }
}

// ---------------- GNN edge update (step s) ----------------
__global__ void __launch_bounds__(256) k_edge(const int* recv1, const int* send1,
    const int* recv2, const int* send2, int s, float* ws)
{
  const float* mir = ws + OFF_MIR;
  __shared__ float ein[4][192];
  int t = threadIdx.x;
  int le = t >> 6, c = t & 63;
  int eidx = blockIdx.x * 4;                 // among 1024 edge-rows (2 graphs)
  const float* n = ws + OFF_N;
  const float* e = ws + OFF_E;
  for (int q = t; q < 768; q += 256) {
    int ee = q / 192, k = q % 192;
    int ge = eidx + ee; int g = ge >> 9, ed = ge & 511;
    const int* recv = g ? recv2 : recv1;
    const int* send = g ? send2 : send1;
    float v;
    if (k < 64)       v = e[(g*512+ed)*64 + k];
    else if (k < 128) v = n[(g*128+recv[ed])*64 + (k-64)];
    else              v = n[(g*128+send[ed])*64 + (k-128)];
    ein[ee][k] = v;
  }
  __syncthreads();
  const float* W = M_WGE + s*192*64;
  float acc = M_BGE[s*64+c];
  for (int k = 0; k < 192; k++) acc += ein[le][k] * W[k*64+c];
  int ge = eidx + le; int g = ge >> 9, ed = ge & 511;
  ws[OFF_E + (g*512+ed)*64 + c] = mila(acc);   // in-place: block owns its 4 rows
}

// ---------------- GNN node update (step s): list gather ----------------
__global__ void __launch_bounds__(64) k_node(const int* recv1, const int* recv2,
    int s, float* ws)
{
  const float* mir = ws + OFF_MIR;
  __shared__ float xin[128];
  int c = threadIdx.x;
  int g = blockIdx.x >> 7, nd = blockIdx.x & 127;
  const float* n = ws + OFF_N;
  const float* e = ws + OFF_E;
  int cnt = ((const int*)ws)[OFF_CNT + g*128 + nd];
  float agg = 0.f;
  if (cnt <= 64) {
    const int* lst = (const int*)ws + OFF_LST + (g*128+nd)*64;
    for (int q = 0; q < cnt; q++) {
      int ed = lst[q];                      // wave-uniform
      agg += e[(g*512+ed)*64 + c];
    }
  } else {                                  // safety fallback (degree > 64)
    const int* recv = g ? recv2 : recv1;
    for (int ed = 0; ed < 512; ed++)
      if (recv[ed] == nd) agg += e[(g*512+ed)*64 + c];
  }
  xin[c] = n[(g*128+nd)*64 + c];
  xin[64 + c] = agg;
  __syncthreads();
  const float* W = M_WGN + s*128*64;
  float acc = M_BGN[s*64+c];
  for (int k = 0; k < 128; k++) acc += xin[k] * W[k*64+c];
  ws[OFF_N + (g*128+nd)*64 + c] = mila(acc);   // in-place: block owns row nd
}

// ---------------- tables A1/A2/B1/B2 + ap MLPs + h-mask ----------------
__global__ void __launch_bounds__(256) k_prep(float* ws)
{
  const float* mir = ws + OFF_MIR;
  __shared__ float sh[4][64], sh2[4][64];
  int t = threadIdx.x;
  const float* n = ws + OFF_N;
  if (blockIdx.x < 128) {
    int T = blockIdx.x >> 5, rg = blockIdx.x & 31;
    int r = rg*4 + (t >> 6), c = t & 63;
    const float* f = (T == 0 || T == 2) ? n : (n + 128*64);
    int wofs = (T == 0 || T == 3) ? 0 : 64;
    float acc = (T == 1 || T == 2) ? M_PPB0[c] : 0.f;
    for (int k = 0; k < 64; k++) acc += f[r*64+k] * M_PPW0[(wofs+k)*64 + c];
    if (T == 0)      ws[OFF_A1 + r*64 + c] = acc;
    else if (T == 1) ws[OFF_A2 + c*128 + r] = acc;
    else if (T == 2) ws[OFF_B1 + r*64 + c] = acc;
    else             ws[OFF_B2 + c*128 + r] = acc;
  } else {
    int b2i = blockIdx.x - 128;
    int g = b2i >> 5, grp = b2i & 31;
    int ln = t >> 6, c = t & 63;
    int nd = grp*4 + ln;
    const float* f = n + (g*128+nd)*64;
    float acc = M_APB0[c];
    for (int k = 0; k < 64; k++) acc += f[k] * M_APW0[k*64+c];
    sh[ln][c] = mila(acc);
    __syncthreads();
    acc = M_APB1[c];
    for (int k = 0; k < 64; k++) acc += sh[ln][k] * M_APW1[k*64+c];
    sh2[ln][c] = mila(acc);
    __syncthreads();
    if (c < 5) {
      float a2 = M_APB2[c];
      for (int k = 0; k < 64; k++) a2 += sh2[ln][k] * M_APW2[k*5+c];
      ws[OFF_APT + (g*5+c)*128 + nd] = ssp_(a2);
    }
    if (c == 0) {
      const float* ns = (g ? M_NODES2 : M_NODES1) + nd*16;
      float v0 = ns[0];
      float ok = 1.f;
      for (int k = 1; k < 16; k++) if (ns[k] > v0) ok = 0.f;
      ws[OFF_HM + g*128 + nd] = ok;
    }
  }
}

// ---------------- pair MLP v3: 512 blocks x 256 threads ----------------
__global__ void __launch_bounds__(256) k_pair(float* ws)
{
  const float* mir = ws + OFF_MIR;
  float* params = ws + OFF_PAR;
  __shared__ float W1s[4096];     // [c][o]
  __shared__ float W2s[320];      // [k][o5]
  __shared__ float b1s[64], b2s[8], bases[64];
  __shared__ float h0s[4096];     // [c][jl] 64x64
  __shared__ float opart[64][4][5];
  int t = threadIdx.x;
  int jl = t & 63, h = t >> 6;
  int i = blockIdx.x >> 2, dir = (blockIdx.x >> 1) & 1, jh = blockIdx.x & 1;
  const float* base = ws + (dir ? OFF_B1 : OFF_A1) + i*64;
  const float* oT   = ws + (dir ? OFF_B2 : OFF_A2) + jh*64;
  #pragma unroll
  for (int q = 0; q < 16; q++) W1s[q*256 + t] = M_PPW1[q*256 + t];
  for (int q = t; q < 320; q += 256) W2s[q] = M_PPW2[q];
  if (t < 64) { b1s[t] = M_PPB1[t]; bases[t] = base[t]; }
  if (t >= 64 && t < 72) b2s[t-64] = (t-64 < 5) ? M_PPB2[t-64] : 0.f;
  __syncthreads();
  #pragma unroll
  for (int q = 0; q < 16; q++) {
    int idx = q*256 + t;
    int c = idx >> 6, j2 = idx & 63;
    h0s[idx] = mila(bases[c] + oT[c*128 + j2]);
  }
  __syncthreads();
  float h1c[16];
  #pragma unroll
  for (int k = 0; k < 16; k++) h1c[k] = b1s[h*16 + k];
  for (int c = 0; c < 64; c++) {
    float h0c = h0s[c*64 + jl];
    const float4* w4 = (const float4*)&W1s[c*64 + h*16];
    float4 wa = w4[0], wb = w4[1], wc = w4[2], wd = w4[3];
    h1c[0]  += h0c*wa.x; h1c[1]  += h0c*wa.y; h1c[2]  += h0c*wa.z; h1c[3]  += h0c*wa.w;
    h1c[4]  += h0c*wb.x; h1c[5]  += h0c*wb.y; h1c[6]  += h0c*wb.z; h1c[7]  += h0c*wb.w;
    h1c[8]  += h0c*wc.x; h1c[9]  += h0c*wc.y; h1c[10] += h0c*wc.z; h1c[11] += h0c*wc.w;
    h1c[12] += h0c*wd.x; h1c[13] += h0c*wd.y; h1c[14] += h0c*wd.z; h1c[15] += h0c*wd.w;
  }
  float o5p[5] = {0.f, 0.f, 0.f, 0.f, 0.f};
  #pragma unroll
  for (int k = 0; k < 16; k++) {
    float hk = mila(h1c[k]);
    int kk = h*16 + k;
    #pragma unroll
    for (int o = 0; o < 5; o++) o5p[o] += hk * W2s[kk*5 + o];
  }
  #pragma unroll
  for (int o = 0; o < 5; o++) opart[jl][h][o] = o5p[o];
  __syncthreads();
  if (t < 64) {
    int p = i*128 + jh*64 + t;
    #pragma unroll
    for (int o = 0; o < 5; o++) {
      float val = b2s[o] + opart[t][0][o] + opart[t][1][o]
                         + opart[t][2][o] + opart[t][3][o];
      atomicAdd(&params[p*5 + o], ssp_(val));
    }
  }
}

// ======== induction (r11 proven): 64 blocks x 512 threads, 2 rows/thread ====
// t = il*8+sub; il in [0,64) owns rows/cols {il, il+64}; sub in [0,8),
// j/i = sub+8*jj (16 steps). Each j-indexed b128 (m2s/c2s, m1s/c1s) read
// serves TWO rows; fixed-row coords hoisted to (few) regs across iters.
// Measured r11: 63 us, LDS-pipe throughput bound.
__global__ void __launch_bounds__(512) k_ind_all(const void* distp, float* ws)
{
  const float* mir = ws + OFF_MIR;
  const float* apT = ws + OFF_APT;
  __shared__ __align__(8) float2 sC35[128*132];
  __shared__ float4 c1s[128], c2s[128], m1s[128], m2s[128];
  __shared__ float4 e01s[128], e02s[128], f1s[128], f2s[128];
  __shared__ float p1s[128], p2s[128], q1s[128], q2s[128];
  __shared__ float esum[128];
  int b = blockIdx.x, t = threadIdx.x;
  bool isbf = ws[OFF_FLAG] != 0.f;
  if (t < 128) {
    c1s[t] = make_float4(M_C1[(b*128+t)*3], M_C1[(b*128+t)*3+1], M_C1[(b*128+t)*3+2], 0.f);
    c2s[t] = make_float4(M_C2[(b*128+t)*3], M_C2[(b*128+t)*3+1], M_C2[(b*128+t)*3+2], 0.f);
    p1s[t] = apT[128 + t];
    p2s[t] = apT[(5+1)*128 + t];
    q1s[t] = M_MP[b*128 + t];
    q2s[t] = M_MP[8192 + b*128 + t];
  }
  __syncthreads();
  int il = t >> 3, sub = t & 7;
  int i0 = il, i1 = il + 64;
  // phase 1: c35 table (LDS) + E0_1 row sums for both rows
  {
    float4 c1a = c1s[i0], c1b = c1s[i1];
    float p1a = p1s[i0], p1b = p1s[i1];
    float eax = 0, eay = 0, eaz = 0, ebx = 0, eby = 0, ebz = 0;
    #pragma unroll 2
    for (int jj = 0; jj < 16; jj++) {
      int j = sub + 8*jj;
      float p2j = p2s[j], q2j = q2s[j];
      float4 c2 = c2s[j];
      {
        float R = rdist(distp, (long)b*16384 + i0*128 + j, isbf);
        float R2 = R*R, R3 = R2*R, R5 = R3*R2;
        float au = sqrtf(p1a * p2j) + 1e-6f;
        float u3 = R3 / au;
        float exu = expf(-0.39f * u3);
        float c3 = (1.f - exu) / (R3 + 1e-6f);
        float c5 = 3.f * (1.f - (1.f + 0.39f*u3) * exu) / (R5 + 1e-6f);
        sC35[i0*132 + j] = make_float2(c3, c5);
        float w = q2j * c3;
        eax += w*(c1a.x - c2.x); eay += w*(c1a.y - c2.y); eaz += w*(c1a.z - c2.z);
      }
      {
        float R = rdist(distp, (long)b*16384 + i1*128 + j, isbf);
        float R2 = R*R, R3 = R2*R, R5 = R3*R2;
        float au = sqrtf(p1b * p2j) + 1e-6f;
        float u3 = R3 / au;
        float exu = expf(-0.39f * u3);
        float c3 = (1.f - exu) / (R3 + 1e-6f);
        float c5 = 3.f * (1.f - (1.f + 0.39f*u3) * exu) / (R5 + 1e-6f);
        sC35[i1*132 + j] = make_float2(c3, c5);
        float w = q2j * c3;
        ebx += w*(c1b.x - c2.x); eby += w*(c1b.y - c2.y); ebz += w*(c1b.z - c2.z);
      }
    }
    #pragma unroll
    for (int m = 1; m <= 4; m <<= 1) {
      eax += __shfl_xor(eax, m, 64); eay += __shfl_xor(eay, m, 64); eaz += __shfl_xor(eaz, m, 64);
      ebx += __shfl_xor(ebx, m, 64); eby += __shfl_xor(eby, m, 64); ebz += __shfl_xor(ebz, m, 64);
    }
    if (sub == 0) {
      e01s[i0] = make_float4(eax, eay, eaz, 0.f);
      e01s[i1] = make_float4(ebx, eby, ebz, 0.f);
    }
  }
  __syncthreads();
  // phase 2: E0_2 col sums for both cols
  {
    float4 c2a = c2s[i0], c2b = c2s[i1];
    float eax = 0, eay = 0, eaz = 0, ebx = 0, eby = 0, ebz = 0;
    #pragma unroll 2
    for (int jj = 0; jj < 16; jj++) {
      int i = sub + 8*jj;
      float4 c1 = c1s[i];
      float q1i = q1s[i];
      float c3a = sC35[i*132 + i0].x;
      float c3b = sC35[i*132 + i1].x;
      float wa = q1i * c3a, wb = q1i * c3b;
      eax -= wa*(c1.x - c2a.x); eay -= wa*(c1.y - c2a.y); eaz -= wa*(c1.z - c2a.z);
      ebx -= wb*(c1.x - c2b.x); eby -= wb*(c1.y - c2b.y); ebz -= wb*(c1.z - c2b.z);
    }
    #pragma unroll
    for (int m = 1; m <= 4; m <<= 1) {
      eax += __shfl_xor(eax, m, 64); eay += __shfl_xor(eay, m, 64); eaz += __shfl_xor(eaz, m, 64);
      ebx += __shfl_xor(ebx, m, 64); eby += __shfl_xor(eby, m, 64); ebz += __shfl_xor(ebz, m, 64);
    }
    if (sub == 0) {
      e02s[i0] = make_float4(eax, eay, eaz, 0.f);
      e02s[i1] = make_float4(ebx, eby, ebz, 0.f);
    }
  }
  __syncthreads();
  if (t < 128) {
    float4 e1 = e01s[t], e2 = e02s[t];
    m1s[t] = make_float4(p1s[t]*e1.x, p1s[t]*e1.y, p1s[t]*e1.z, 0.f);
    m2s[t] = make_float4(p2s[t]*e2.x, p2s[t]*e2.y, p2s[t]*e2.z, 0.f);
  }
  __syncthreads();
  // hoisted fixed-row/col coords (static across iterations)
  float4 c1a = c1s[i0], c1b = c1s[i1];
  float4 c2a = c2s[i0], c2b = c2s[i1];
  // 8 Jacobi iterations, block-local sync
  for (int it = 0; it < 8; it++) {
    // pass A: f1[i0], f1[i1] — one m2s/c2s read serves both rows
    {
      float fax = 0, fay = 0, faz = 0, fbx = 0, fby = 0, fbz = 0;
      #pragma unroll 2
      for (int jj = 0; jj < 16; jj++) {
        int j = sub + 8*jj;
        float2 cca = sC35[i0*132 + j];
        float2 ccb = sC35[i1*132 + j];
        float4 m2 = m2s[j], c2 = c2s[j];
        {
          float rx = c1a.x - c2.x, ry = c1a.y - c2.y, rz = c1a.z - c2.z;
          float dot = rx*m2.x + ry*m2.y + rz*m2.z;
          float a = cca.y * dot;
          fax += a*rx - cca.x*m2.x; fay += a*ry - cca.x*m2.y; faz += a*rz - cca.x*m2.z;
        }
        {
          float rx = c1b.x - c2.x, ry = c1b.y - c2.y, rz = c1b.z - c2.z;
          float dot = rx*m2.x + ry*m2.y + rz*m2.z;
          float a = ccb.y * dot;
          fbx += a*rx - ccb.x*m2.x; fby += a*ry - ccb.x*m2.y; fbz += a*rz - ccb.x*m2.z;
        }
      }
      #pragma unroll
      for (int m = 1; m <= 4; m <<= 1) {
        fax += __shfl_xor(fax, m, 64); fay += __shfl_xor(fay, m, 64); faz += __shfl_xor(faz, m, 64);
        fbx += __shfl_xor(fbx, m, 64); fby += __shfl_xor(fby, m, 64); fbz += __shfl_xor(fbz, m, 64);
      }
      if (sub == 0) {
        f1s[i0] = make_float4(fax, fay, faz, 0.f);
        f1s[i1] = make_float4(fbx, fby, fbz, 0.f);
      }
    }
    // pass B: f2[j0], f2[j1] — one m1s/c1s read serves both cols
    {
      float fax = 0, fay = 0, faz = 0, fbx = 0, fby = 0, fbz = 0;
      #pragma unroll 2
      for (int jj = 0; jj < 16; jj++) {
        int i = sub + 8*jj;
        float2 cca = sC35[i*132 + i0];
        float2 ccb = sC35[i*132 + i1];
        float4 m1 = m1s[i], c1 = c1s[i];
        {
          float rx = c1.x - c2a.x, ry = c1.y - c2a.y, rz = c1.z - c2a.z;
          float dot = rx*m1.x + ry*m1.y + rz*m1.z;
          float a = cca.y * dot;
          fax += a*rx - cca.x*m1.x; fay += a*ry - cca.x*m1.y; faz += a*rz - cca.x*m1.z;
        }
        {
          float rx = c1.x - c2b.x, ry = c1.y - c2b.y, rz = c1.z - c2b.z;
          float dot = rx*m1.x + ry*m1.y + rz*m1.z;
          float a = ccb.y * dot;
          fbx += a*rx - ccb.x*m1.x; fby += a*ry - ccb.x*m1.y; fbz += a*rz - ccb.x*m1.z;
        }
      }
      #pragma unroll
      for (int m = 1; m <= 4; m <<= 1) {
        fax += __shfl_xor(fax, m, 64); fay += __shfl_xor(fay, m, 64); faz += __shfl_xor(faz, m, 64);
        fbx += __shfl_xor(fbx, m, 64); fby += __shfl_xor(fby, m, 64); fbz += __shfl_xor(fbz, m, 64);
      }
      if (sub == 0) {
        f2s[i0] = make_float4(fax, fay, faz, 0.f);
        f2s[i1] = make_float4(fbx, fby, fbz, 0.f);
      }
    }
    __syncthreads();
    if (t < 128) {
      float4 f1 = f1s[t], e1 = e01s[t], mo1 = m1s[t];
      float4 f2 = f2s[t], e2 = e02s[t], mo2 = m2s[t];
      float p1 = p1s[t], p2 = p2s[t];
      m1s[t] = make_float4(0.25f*mo1.x + 0.75f*p1*(e1.x + f1.x),
                           0.25f*mo1.y + 0.75f*p1*(e1.y + f1.y),
                           0.25f*mo1.z + 0.75f*p1*(e1.z + f1.z), 0.f);
      m2s[t] = make_float4(0.25f*mo2.x + 0.75f*p2*(e2.x + f2.x),
                           0.25f*mo2.y + 0.75f*p2*(e2.y + f2.y),
                           0.25f*mo2.z + 0.75f*p2*(e2.z + f2.z), 0.f);
    }
    __syncthreads();
  }
  // energy + mu store
  if (t < 128) {
    float4 m1 = m1s[t], m2 = m2s[t], e1 = e01s[t], e2 = e02s[t];
    esum[t] = m1.x*e1.x + m1.y*e1.y + m1.z*e1.z
            + m2.x*e2.x + m2.y*e2.y + m2.z*e2.z;
    *(float4*)&ws[OFF_MU1 + (b*128+t)*4] = m1;
    *(float4*)&ws[OFF_MU2 + (b*128+t)*4] = m2;
  }
  __syncthreads();
  if (t == 0) {
    float s = 0.f;
    for (int k = 0; k < 128; k++) s += esum[k];
    ws[OFF_ACC + 64 + b] = -0.5f * s;     // ct subtracted by k_terms
  }
}

// ---------------- es / ex / disp / ct terms: 1024 blocks ----------------
__global__ void __launch_bounds__(256) k_terms(const void* distp, float* ws)
{
  const float* mir = ws + OFF_MIR;
  int b = blockIdx.x >> 4, q = blockIdx.x & 15;
  int t = threadIdx.x;
  bool isbf = ws[OFF_FLAG] != 0.f;
  const float* par = ws + OFF_PAR;
  const float* apT = ws + OFF_APT;
  const float* hm  = ws + OFF_HM;
  const float* mu1 = ws + OFF_MU1;
  const float* mu2 = ws + OFF_MU2;
  float es = 0, ct = 0, ex = 0, dp = 0;
  for (int s = 0; s < 4; s++) {
    int p = q*1024 + s*256 + t;
    int i = p >> 7, j = p & 127;
    float C6 = par[p*5+0], C8 = par[p*5+1], C10 = par[p*5+2];
    float Act = par[p*5+3], bct = par[p*5+4];
    float R = rdist(distp, (long)b*16384 + p, isbf);
    float Rs = R + 1e-6f;
    float B0 = 1.f / Rs;
    float R2 = R*R;
    float R6 = R2*R2*R2, R8 = R6*R2, R10 = R8*R2;
    float r0 = C8 / (C6 + 1e-6f);
    float D6 = r0*r0*r0, D8 = D6*r0, D10 = D8*r0;
    if (R2 < 2500.f) dp -= C6/(R6+D6) + C8/(R8+D8) + C10/(R10+D10);
    ct += Act * expf(-bct * R);
    float q1v = M_MP[b*128 + i];
    float q2v = M_MP[8192 + b*128 + j];
    float ad1 = apT[0*128 + i],   ad2 = apT[(5+0)*128 + j];
    float k1v = apT[2*128 + i],   k2v = apT[(5+2)*128 + j];
    float ae1 = apT[4*128 + i],   ae2 = apT[(5+4)*128 + j];
    float dq1 = apT[3*128 + i],   dq2 = apT[(5+3)*128 + j];
    float bd = sqrtf(ad1*ad2), be = sqrtf(ae1*ae2), Kp = k1v*k2v;
    float ebd = expf(-bd * R);
    float fd = 1.f - (1.f + 0.5f*bd*R) * ebd;
    es += q1v * q2v * fd * B0;
    float rxx = M_C2[(b*128+j)*3+0] - M_C1[(b*128+i)*3+0];
    float rxy = M_C2[(b*128+j)*3+1] - M_C1[(b*128+i)*3+1];
    float rxz = M_C2[(b*128+j)*3+2] - M_C1[(b*128+i)*3+2];
    float m1x = mu1[(b*128+i)*4+0], m1y = mu1[(b*128+i)*4+1], m1z = mu1[(b*128+i)*4+2];
    float m2x = mu2[(b*128+j)*4+0], m2y = mu2[(b*128+j)*4+1], m2z = mu2[(b*128+j)*4+2];
    float proj = ((m1x-m2x)*rxx + (m1y-m2y)*rxy + (m1z-m2z)*rxz) * B0;
    float h1v = hm[i], h2v = hm[128 + j];
    float qe1 = h1v > 0.5f ? (1.f - q1v) : (2.f + dq1 - q1v);
    float qe2 = h2v > 0.5f ? (1.f - q2v) : (2.f + dq2 - q2v);
    ex += Kp * qe1 * qe2 * (1.f + proj) * expf(-be * R) * B0;
  }
  __shared__ float sred[4][4];
  for (int m = 32; m >= 1; m >>= 1) {
    es += __shfl_xor(es, m, 64); ct += __shfl_xor(ct, m, 64);
    ex += __shfl_xor(ex, m, 64); dp += __shfl_xor(dp, m, 64);
  }
  int w = t >> 6;
  if ((t & 63) == 0) { sred[w][0] = es; sred[w][1] = ct; sred[w][2] = ex; sred[w][3] = dp; }
  __syncthreads();
  if (t == 0) {
    float a0 = 0, a1 = 0, a2 = 0, a3 = 0;
    for (int ww = 0; ww < 4; ww++) { a0 += sred[ww][0]; a1 += sred[ww][1]; a2 += sred[ww][2]; a3 += sred[ww][3]; }
    atomicAdd(&ws[OFF_ACC +   0 + b], a0);   // es
    atomicAdd(&ws[OFF_ACC +  64 + b], -a1);  // in -= ct
    atomicAdd(&ws[OFF_ACC + 128 + b], a2);   // ex
    atomicAdd(&ws[OFF_ACC + 192 + b], a3);   // disp
  }
}

// ---------------- finalize: total + dtype-matched output ----------------
__global__ void __launch_bounds__(64) k_total(const float* ws, void* outv)
{
  int b = threadIdx.x;
  float es  = ws[OFF_ACC +   0 + b];
  float inv = ws[OFF_ACC +  64 + b];
  float ex  = ws[OFF_ACC + 128 + b];
  float dp  = ws[OFF_ACC + 192 + b];
  float tot = ex + dp + es + inv;
  if (ws[OFF_FLAG] != 0.f) {
    unsigned short* out = (unsigned short*)outv;
    out[b]       = f2b(tot);
    out[64 + b]  = f2b(es);
    out[128 + b] = f2b(inv);
    out[192 + b] = f2b(ex);
    out[256 + b] = f2b(dp);
  } else {
    float* out = (float*)outv;
    out[b]       = tot;
    out[64 + b]  = es;
    out[128 + b] = inv;
    out[192 + b] = ex;
    out[256 + b] = dp;
  }
}

extern "C" void kernel_launch(void* const* d_in, const int* in_sizes, int n_in,
                              void* d_out, int out_size, void* d_ws, size_t ws_size,
                              hipStream_t stream)
{
  const int* send1 = (const int*)d_in[2];
  const int* recv1 = (const int*)d_in[3];
  const int* send2 = (const int*)d_in[6];
  const int* recv2 = (const int*)d_in[7];
  float* ws = (float*)d_ws;

  k_convert<<<959, 256, 0, stream>>>(
      d_in[0], d_in[1], d_in[4], d_in[5], d_in[8], d_in[9], d_in[11],
      d_in[12], d_in[13], d_in[14], d_in[15], d_in[16], d_in[17], d_in[18],
      d_in[19], d_in[20], d_in[21], d_in[22], d_in[23], d_in[24], d_in[25],
      d_in[26], d_in[27], d_in[28], d_in[29], d_in[30], d_in[31],
      d_in[10], recv1, recv2, ws);

  k_emb<<<320, 256, 0, stream>>>(ws);
  for (int s = 0; s < 3; s++) {
    k_edge<<<256, 256, 0, stream>>>(recv1, send1, recv2, send2, s, ws);
    k_node<<<256, 64, 0, stream>>>(recv1, recv2, s, ws);
  }
  k_prep<<<192, 256, 0, stream>>>(ws);
  k_pair<<<512, 256, 0, stream>>>(ws);
  k_ind_all<<<64, 512, 0, stream>>>(d_in[10], ws);
  k_terms<<<1024, 256, 0, stream>>>(d_in[10], ws);
  k_total<<<1, 64, 0, stream>>>(ws, d_out);
}